// Round 6
// baseline (472.612 us; speedup 1.0000x reference)
//
#include <hip/hip_runtime.h>
#include <hip/hip_bf16.h>

#define DIM 768
#define HEADS 12
#define HD 64
#define HIDDEN 3072
#define SEQ 1024
#define NB 8
#define M_TOK (NB * SEQ)   // 8192 tokens
#define C3 (3 * DIM)       // 2304

typedef __attribute__((ext_vector_type(8))) short short8;    // 8 x bf16 (4 VGPRs)
typedef __attribute__((ext_vector_type(4))) short shortx4;   // 4 x bf16 (8B)
typedef __attribute__((ext_vector_type(4))) float floatx4;   // MFMA accum

__device__ __forceinline__ void gload_lds16(const void* g, void* l) {
  __builtin_amdgcn_global_load_lds((const __attribute__((address_space(1))) void*)g,
                                   (__attribute__((address_space(3))) void*)l, 16, 0, 0);
}

__device__ __forceinline__ unsigned short bf16b(float f) {
  __hip_bfloat16 h = __float2bfloat16(f);
  return *(unsigned short*)&h;
}

// ---------------------------------------------------------------------------
// Weight transpose + f32->bf16 cast: w[K][N] -> wt[N][K]
// ---------------------------------------------------------------------------
__global__ __launch_bounds__(256) void transpose_cast(
    const float* __restrict__ w, __hip_bfloat16* __restrict__ wt, int K, int N) {
  __shared__ float tile[32][33];
  const int tx = threadIdx.x & 31, ty = threadIdx.x >> 5;
  const int n0 = blockIdx.x * 32, k0 = blockIdx.y * 32;
#pragma unroll
  for (int i = 0; i < 32; i += 8)
    tile[ty + i][tx] = w[(size_t)(k0 + ty + i) * N + n0 + tx];
  __syncthreads();
#pragma unroll
  for (int i = 0; i < 32; i += 8)
    wt[(size_t)(n0 + ty + i) * K + k0 + tx] = __float2bfloat16(tile[tx][ty + i]);
}

// ---------------------------------------------------------------------------
// LayerNorm (f32 in) -> bf16 out.  One block per row of 768.
// ---------------------------------------------------------------------------
__global__ __launch_bounds__(256) void ln_kernel(
    const float* __restrict__ x, const float* __restrict__ gw,
    const float* __restrict__ bw, __hip_bfloat16* __restrict__ outp) {
  const int row = blockIdx.x;
  const int t = threadIdx.x;
  const float* xr = x + (size_t)row * DIM;
  float v0 = xr[t], v1 = xr[t + 256], v2 = xr[t + 512];
  float s = v0 + v1 + v2;
  float sq = v0 * v0 + v1 * v1 + v2 * v2;
#pragma unroll
  for (int m = 1; m < 64; m <<= 1) {
    s += __shfl_xor(s, m);
    sq += __shfl_xor(sq, m);
  }
  __shared__ float ss[4], ssq[4];
  const int wave = t >> 6, lane = t & 63;
  if (lane == 0) { ss[wave] = s; ssq[wave] = sq; }
  __syncthreads();
  s = ss[0] + ss[1] + ss[2] + ss[3];
  sq = ssq[0] + ssq[1] + ssq[2] + ssq[3];
  const float mean = s * (1.f / 768.f);
  const float var = sq * (1.f / 768.f) - mean * mean;
  const float rstd = rsqrtf(var + 1e-5f);
  __hip_bfloat16* orow = outp + (size_t)row * DIM;
  orow[t]       = __float2bfloat16((v0 - mean) * rstd * gw[t]       + bw[t]);
  orow[t + 256] = __float2bfloat16((v1 - mean) * rstd * gw[t + 256] + bw[t + 256]);
  orow[t + 512] = __float2bfloat16((v2 - mean) * rstd * gw[t + 512] + bw[t + 512]);
}

// ---------------------------------------------------------------------------
// 256x256 GEMM, BK=64, 8 waves (2M x 4N), counted-vmcnt 2-deep prefetch,
// XOR-swizzled LDS (pre-swizzled global source), setprio'd MFMA phases.
// K-chunk per block = 768 (12 tiles); full-K row stride passed as K.
// OUTMODE: 1 = bf16 out (+bias/gelu), 2 = qkv scatter, 3 = f32 atomicAdd
// (+bias when blockIdx.z==0; used for split-K fc2 onto x_mid in d_out).
// ---------------------------------------------------------------------------
template <int BIAS, int GELU, int OUTMODE>
__global__ __launch_bounds__(512, 2) void gemm256(
    const __hip_bfloat16* __restrict__ A, const __hip_bfloat16* __restrict__ BT,
    const float* __restrict__ bias, void* __restrict__ Cout,
    __hip_bfloat16* __restrict__ Qc, __hip_bfloat16* __restrict__ Kc,
    __hip_bfloat16* __restrict__ Vt,
    int N, int K) {
  __shared__ __align__(16) __hip_bfloat16 Al[2][256 * 64];
  __shared__ __align__(16) __hip_bfloat16 Bl[2][256 * 64];
  const int tid = threadIdx.x;
  const int wave = tid >> 6, lane = tid & 63;
  const int g = lane >> 4, fr = lane & 15;
  const int wm = wave >> 2, wn = wave & 3;  // 2M x 4N waves

  // bijective XCD swizzle on the x-y plane (nwg % 8 == 0 for all launches)
  const int gx = gridDim.x;
  const int nwg = gx * gridDim.y;
  int bi = blockIdx.y * gx + blockIdx.x;
  bi = (bi & 7) * (nwg >> 3) + (bi >> 3);
  const int m0 = (bi / gx) * 256, n0 = (bi % gx) * 256;
  const int k0 = blockIdx.z * 768;

  // stage one 256x64 tile of A and B; LDS linear dest, source chunk ^(row&7)
  auto stage = [&](int slot, int kt) {
#pragma unroll
    for (int i = 0; i < 4; ++i) {
      const int idx = i * 512 + tid;
      const int row = idx >> 3, c = idx & 7;
      const int sc = (c ^ (row & 7)) << 3;
      gload_lds16(A + (size_t)(m0 + row) * K + kt + sc, &Al[slot][idx * 8]);
    }
#pragma unroll
    for (int i = 0; i < 4; ++i) {
      const int idx = i * 512 + tid;
      const int row = idx >> 3, c = idx & 7;
      const int sc = (c ^ (row & 7)) << 3;
      gload_lds16(BT + (size_t)(n0 + row) * K + kt + sc, &Bl[slot][idx * 8]);
    }
  };

  floatx4 acc[8][4];
  const floatx4 zero = {0.f, 0.f, 0.f, 0.f};
#pragma unroll
  for (int mf = 0; mf < 8; ++mf)
#pragma unroll
    for (int nf = 0; nf < 4; ++nf) acc[mf][nf] = zero;

  stage(0, k0);
  stage(1, k0 + 64);
  asm volatile("s_waitcnt vmcnt(8)" ::: "memory");
  __builtin_amdgcn_s_barrier();
  asm volatile("" ::: "memory");

#pragma unroll 1
  for (int t = 0; t < 12; ++t) {
    const __hip_bfloat16* Ab = Al[t & 1];
    const __hip_bfloat16* Bb = Bl[t & 1];
    // B fragments for the whole tile (held across phases)
    short8 bfr[4][2];
#pragma unroll
    for (int nf = 0; nf < 4; ++nf)
#pragma unroll
      for (int kh = 0; kh < 2; ++kh) {
        const int row = wn * 64 + nf * 16 + fr;
        bfr[nf][kh] = *(const short8*)(Bb + row * 64 + (((kh * 4 + g) ^ (row & 7)) << 3));
      }
    // 4 phases: 2 M-frags x 4 N-frags x K64 = 16 MFMA each
#pragma unroll
    for (int p = 0; p < 4; ++p) {
      short8 afr[2][2];
#pragma unroll
      for (int s = 0; s < 2; ++s)
#pragma unroll
        for (int kh = 0; kh < 2; ++kh) {
          const int row = wm * 128 + (p * 2 + s) * 16 + fr;
          afr[s][kh] = *(const short8*)(Ab + row * 64 + (((kh * 4 + g) ^ (row & 7)) << 3));
        }
      __builtin_amdgcn_s_setprio(1);
#pragma unroll
      for (int s = 0; s < 2; ++s)
#pragma unroll
        for (int nf = 0; nf < 4; ++nf)
#pragma unroll
          for (int kh = 0; kh < 2; ++kh)
            acc[p * 2 + s][nf] = __builtin_amdgcn_mfma_f32_16x16x32_bf16(
                afr[s][kh], bfr[nf][kh], acc[p * 2 + s][nf], 0, 0, 0);
      __builtin_amdgcn_s_setprio(0);
    }
    if (t == 11) break;
    // boundary: all waves done reading slot (t&1) -> safe to overwrite
    asm volatile("" ::: "memory");
    __builtin_amdgcn_s_barrier();
    asm volatile("" ::: "memory");
    if (t + 2 < 12) {
      stage(t & 1, k0 + (t + 2) * 64);
      asm volatile("s_waitcnt vmcnt(8)" ::: "memory");  // slot (t+1)&1 landed
    } else {
      asm volatile("s_waitcnt vmcnt(0)" ::: "memory");  // last tile landed
    }
    __builtin_amdgcn_s_barrier();
    asm volatile("" ::: "memory");
  }

  // ---- epilogue ----
#pragma unroll
  for (int mf = 0; mf < 8; ++mf) {
    const int row = m0 + wm * 128 + mf * 16 + g * 4;
#pragma unroll
    for (int nf = 0; nf < 4; ++nf) {
      const int col = n0 + wn * 64 + nf * 16 + fr;
      if (OUTMODE == 2) {
        const int part = (col >= 1536) ? 2 : (col >= 768 ? 1 : 0);
        const int cc = col - part * 768;
        const int h = cc >> 6, d = cc & 63;
        const int b = row >> 10, s = row & 1023;  // row%4==0: s..s+3 same b
        const size_t hb = (size_t)b * HEADS + h;
        if (part == 2) {
          shortx4 pk;
#pragma unroll
          for (int r = 0; r < 4; ++r) pk[r] = (short)bf16b(acc[mf][nf][r]);
          *(shortx4*)(Vt + (hb * HD + d) * SEQ + s) = pk;
        } else {
          __hip_bfloat16* dst = (part ? Kc : Qc) + (hb * SEQ + s) * HD + d;
#pragma unroll
          for (int r = 0; r < 4; ++r) dst[(size_t)r * HD] = __float2bfloat16(acc[mf][nf][r]);
        }
      } else if (OUTMODE == 3) {
        const float bv = (BIAS && blockIdx.z == 0) ? bias[col] : 0.f;
#pragma unroll
        for (int r = 0; r < 4; ++r)
          atomicAdd((float*)Cout + (size_t)(row + r) * N + col, acc[mf][nf][r] + bv);
      } else {
        const float bv = BIAS ? bias[col] : 0.f;
#pragma unroll
        for (int r = 0; r < 4; ++r) {
          float c = acc[mf][nf][r] + bv;
          if (GELU) c = 0.5f * c * (1.f + erff(c * 0.70710678118f));
          ((__hip_bfloat16*)Cout)[(size_t)(row + r) * N + col] = __float2bfloat16(c);
        }
      }
    }
  }
}

// ---------------------------------------------------------------------------
// 128x128 GEMM (m97 structure) — kept for proj (small N).
// ---------------------------------------------------------------------------
template <int BIAS, int GELU, int RES, int OUTMODE>
__global__ __launch_bounds__(256) void gemm_bt(
    const __hip_bfloat16* __restrict__ A, const __hip_bfloat16* __restrict__ BT,
    const float* __restrict__ bias, const float* __restrict__ resid,
    void* __restrict__ Cout,
    int M, int N, int K) {
  __shared__ __align__(16) __hip_bfloat16 As[128 * 64];
  __shared__ __align__(16) __hip_bfloat16 Bs[128 * 64];
  const int tid = threadIdx.x;
  const int wave = tid >> 6, lane = tid & 63;
  const int g = lane >> 4, fr = lane & 15;

  const int gx = gridDim.x;
  const int nwg = gx * gridDim.y;
  int bi = blockIdx.y * gx + blockIdx.x;
  bi = (bi & 7) * (nwg >> 3) + (bi >> 3);
  const int m0 = (bi / gx) * 128, n0 = (bi % gx) * 128;
  const int wm = (wave >> 1) * 64, wn = (wave & 1) * 64;

  floatx4 acc[4][4];
  const floatx4 zero = {0.f, 0.f, 0.f, 0.f};
#pragma unroll
  for (int m = 0; m < 4; ++m)
#pragma unroll
    for (int n = 0; n < 4; ++n) acc[m][n] = zero;

  for (int kt = 0; kt < K; kt += 64) {
#pragma unroll
    for (int i = 0; i < 4; ++i) {
      const int li = i * 256 + tid;
      const int row = li >> 3, k8 = (li & 7) << 3;
      gload_lds16(A + (size_t)(m0 + row) * K + kt + k8, As + li * 8);
      gload_lds16(BT + (size_t)(n0 + row) * K + kt + k8, Bs + li * 8);
    }
    __syncthreads();
#pragma unroll
    for (int kk = 0; kk < 64; kk += 32) {
      short8 af[4], bfr[4];
#pragma unroll
      for (int m = 0; m < 4; ++m)
        af[m] = *(const short8*)(As + (wm + m * 16 + fr) * 64 + kk + g * 8);
#pragma unroll
      for (int n = 0; n < 4; ++n)
        bfr[n] = *(const short8*)(Bs + (wn + n * 16 + fr) * 64 + kk + g * 8);
#pragma unroll
      for (int m = 0; m < 4; ++m)
#pragma unroll
        for (int n = 0; n < 4; ++n)
          acc[m][n] = __builtin_amdgcn_mfma_f32_16x16x32_bf16(af[m], bfr[n], acc[m][n], 0, 0, 0);
    }
    __syncthreads();
  }

#pragma unroll
  for (int m = 0; m < 4; ++m) {
    const int row = m0 + wm + m * 16 + g * 4;
#pragma unroll
    for (int n = 0; n < 4; ++n) {
      const int col = n0 + wn + n * 16 + fr;
      const float bv = BIAS ? bias[col] : 0.f;
#pragma unroll
      for (int r = 0; r < 4; ++r) {
        float c = acc[m][n][r] + bv;
        if (GELU) c = 0.5f * c * (1.f + erff(c * 0.70710678118f));
        const size_t off = (size_t)(row + r) * N + col;
        if (RES) c += resid[off];
        if (OUTMODE == 1) ((__hip_bfloat16*)Cout)[off] = __float2bfloat16(c);
        else              ((float*)Cout)[off] = c;
      }
    }
  }
}

// ---------------------------------------------------------------------------
// Flash attention, swapped-operand + block-cooperative LDS staging (R5).
// ---------------------------------------------------------------------------
__global__ __launch_bounds__(256) void attn_kernel(
    const __hip_bfloat16* __restrict__ Qc, const __hip_bfloat16* __restrict__ Kc,
    const __hip_bfloat16* __restrict__ Vt, __hip_bfloat16* __restrict__ outp) {
  const int tid = threadIdx.x;
  const int wave = tid >> 6, lane = tid & 63;
  const int g = lane >> 4, fr = lane & 15;

  int bi = blockIdx.y * gridDim.x + blockIdx.x;
  bi = (bi & 7) * 192 + (bi >> 3);
  const int qt = bi & 15, bh = bi >> 4;
  const int b = bh / HEADS, h = bh % HEADS;
  const int q0 = qt * 64 + wave * 16;

  const __hip_bfloat16* qp = Qc + ((size_t)bh * SEQ + q0 + fr) * HD;
  const short8 qf0 = *(const short8*)(qp + g * 8);
  const short8 qf1 = *(const short8*)(qp + 32 + g * 8);

  const __hip_bfloat16* kbase = Kc + (size_t)bh * SEQ * HD;
  const __hip_bfloat16* vbase = Vt + (size_t)bh * HD * SEQ;

  __shared__ __align__(16) __hip_bfloat16 Kl[2][64 * 64];
  __shared__ __align__(16) __hip_bfloat16 Vl[2][64 * 64];
  __shared__ __align__(16) char P[4][2048];
  char* const pw = P[wave];
  const int swz = (fr & 7) << 4;
  const int rs3 = fr & 7;

  auto stage = [&](int buf, int kt) {
#pragma unroll
    for (int s = 0; s < 2; ++s) {
      const int idx = s * 256 + tid;
      const int row = idx >> 3, c = idx & 7;
      const int sc = c ^ (row & 7);
      gload_lds16(kbase + (size_t)(kt + row) * HD + sc * 8, &Kl[buf][idx * 8]);
      gload_lds16(vbase + (size_t)row * SEQ + kt + sc * 8, &Vl[buf][idx * 8]);
    }
  };

  float m_r = -1e30f, l_r = 0.f;
  floatx4 acc[4];
  const floatx4 zero = {0.f, 0.f, 0.f, 0.f};
#pragma unroll
  for (int n = 0; n < 4; ++n) acc[n] = zero;

  stage(0, 0);
  asm volatile("s_waitcnt vmcnt(0)" ::: "memory");
  __builtin_amdgcn_s_barrier();

  int cur = 0;
  for (int kt = 0; kt < SEQ; kt += 64) {
    if (kt + 64 < SEQ) stage(cur ^ 1, kt + 64);
    const __hip_bfloat16* kl = Kl[cur];
    const __hip_bfloat16* vl = Vl[cur];

    floatx4 sa[4];
#pragma unroll
    for (int t = 0; t < 4; ++t) {
      const int row = t * 16 + fr;
      const short8 k0 = *(const short8*)(kl + row * 64 + ((g ^ rs3) << 3));
      const short8 k1 = *(const short8*)(kl + row * 64 + (((4 + g) ^ rs3) << 3));
      sa[t] = __builtin_amdgcn_mfma_f32_16x16x32_bf16(k0, qf0, zero, 0, 0, 0);
      sa[t] = __builtin_amdgcn_mfma_f32_16x16x32_bf16(k1, qf1, sa[t], 0, 0, 0);
    }
    float mx = -1e30f;
#pragma unroll
    for (int t = 0; t < 4; ++t)
#pragma unroll
      for (int r = 0; r < 4; ++r) mx = fmaxf(mx, sa[t][r]);
    mx *= 0.125f;
    mx = fmaxf(mx, __shfl_xor(mx, 16));
    mx = fmaxf(mx, __shfl_xor(mx, 32));
    const float mn = fmaxf(m_r, mx);
    const float alpha = __expf(m_r - mn);
    float rsum = 0.f;
#pragma unroll
    for (int t = 0; t < 4; ++t)
#pragma unroll
      for (int r2 = 0; r2 < 4; r2 += 2) {
        const float p0 = __expf(sa[t][r2]     * 0.125f - mn);
        const float p1 = __expf(sa[t][r2 + 1] * 0.125f - mn);
        rsum += p0 + p1;
        const unsigned int word = ((unsigned int)bf16b(p1) << 16) | bf16b(p0);
        const int k = t * 16 + g * 4 + r2;
        *(unsigned int*)(pw + fr * 128 + ((k * 2) ^ swz)) = word;
      }
    rsum += __shfl_xor(rsum, 16);
    rsum += __shfl_xor(rsum, 32);
    l_r = l_r * alpha + rsum;
    m_r = mn;
#pragma unroll
    for (int n = 0; n < 4; ++n) acc[n] *= alpha;
    asm volatile("s_waitcnt lgkmcnt(0)" ::: "memory");
    __builtin_amdgcn_sched_barrier(0);
    const short8 pb0 = *(const short8*)(pw + fr * 128 + ((g * 16)      ^ swz));
    const short8 pb1 = *(const short8*)(pw + fr * 128 + ((64 + g * 16) ^ swz));
#pragma unroll
    for (int n = 0; n < 4; ++n) {
      const int d = n * 16 + fr;
      const short8 va0 = *(const short8*)(vl + d * 64 + ((g ^ rs3) << 3));
      const short8 va1 = *(const short8*)(vl + d * 64 + (((4 + g) ^ rs3) << 3));
      acc[n] = __builtin_amdgcn_mfma_f32_16x16x32_bf16(va0, pb0, acc[n], 0, 0, 0);
      acc[n] = __builtin_amdgcn_mfma_f32_16x16x32_bf16(va1, pb1, acc[n], 0, 0, 0);
    }
    asm volatile("s_waitcnt vmcnt(0) lgkmcnt(0)" ::: "memory");
    __builtin_amdgcn_s_barrier();
    cur ^= 1;
  }

  const float inv_l = 1.f / l_r;
  __hip_bfloat16* op = outp + (size_t)(b * SEQ + q0 + fr) * DIM + h * HD + g * 4;
#pragma unroll
  for (int n = 0; n < 4; ++n) {
    shortx4 pk;
#pragma unroll
    for (int r = 0; r < 4; ++r) pk[r] = (short)bf16b(acc[n][r] * inv_l);
    *(shortx4*)(op + n * 16) = pk;
  }
}

// ---------------------------------------------------------------------------
extern "C" void kernel_launch(void* const* d_in, const int* in_sizes, int n_in,
                              void* d_out, int out_size, void* d_ws, size_t ws_size,
                              hipStream_t stream) {
  (void)in_sizes; (void)n_in; (void)out_size; (void)ws_size;
  const float* x      = (const float*)d_in[0];
  const float* ln1_g  = (const float*)d_in[1];
  const float* ln1_b  = (const float*)d_in[2];
  const float* w_qkv  = (const float*)d_in[3];
  const float* w_proj = (const float*)d_in[4];
  const float* b_proj = (const float*)d_in[5];
  const float* ln2_g  = (const float*)d_in[6];
  const float* ln2_b  = (const float*)d_in[7];
  const float* w_fc1  = (const float*)d_in[8];
  const float* b_fc1  = (const float*)d_in[9];
  const float* w_fc2  = (const float*)d_in[10];
  const float* b_fc2  = (const float*)d_in[11];
  float* outp = (float*)d_out;

  char* ws = (char*)d_ws;
  size_t off = 0;
  auto alloc = [&](size_t bytes) -> void* {
    void* p = ws + off;
    off += (bytes + 255) & ~(size_t)255;
    return p;
  };
  __hip_bfloat16* h1     = (__hip_bfloat16*)alloc((size_t)M_TOK * DIM * 2);
  __hip_bfloat16* Qc     = (__hip_bfloat16*)alloc((size_t)M_TOK * DIM * 2);
  __hip_bfloat16* Kc     = (__hip_bfloat16*)alloc((size_t)M_TOK * DIM * 2);
  __hip_bfloat16* Vt     = (__hip_bfloat16*)alloc((size_t)M_TOK * DIM * 2);
  __hip_bfloat16* att    = (__hip_bfloat16*)alloc((size_t)M_TOK * DIM * 2);
  __hip_bfloat16* h2     = (__hip_bfloat16*)alloc((size_t)M_TOK * DIM * 2);
  __hip_bfloat16* act    = (__hip_bfloat16*)alloc((size_t)M_TOK * HIDDEN * 2);
  __hip_bfloat16* wqkvT  = (__hip_bfloat16*)alloc((size_t)C3 * DIM * 2);
  __hip_bfloat16* wprojT = (__hip_bfloat16*)alloc((size_t)DIM * DIM * 2);
  __hip_bfloat16* wfc1T  = (__hip_bfloat16*)alloc((size_t)HIDDEN * DIM * 2);
  __hip_bfloat16* wfc2T  = (__hip_bfloat16*)alloc((size_t)DIM * HIDDEN * 2);
  float* x_mid = outp;  // mid-residual lives in d_out (fully rewritten each call)

  transpose_cast<<<dim3(C3 / 32, DIM / 32), 256, 0, stream>>>(w_qkv, wqkvT, DIM, C3);
  transpose_cast<<<dim3(DIM / 32, DIM / 32), 256, 0, stream>>>(w_proj, wprojT, DIM, DIM);
  transpose_cast<<<dim3(HIDDEN / 32, DIM / 32), 256, 0, stream>>>(w_fc1, wfc1T, DIM, HIDDEN);
  transpose_cast<<<dim3(DIM / 32, HIDDEN / 32), 256, 0, stream>>>(w_fc2, wfc2T, HIDDEN, DIM);

  ln_kernel<<<M_TOK, 256, 0, stream>>>(x, ln1_g, ln1_b, h1);
  // qkv: M=8192, N=2304, K=768 -> 32x9 = 288 blocks, scatter epilogue
  gemm256<0, 0, 2><<<dim3(C3 / 256, M_TOK / 256), 512, 0, stream>>>(
      h1, wqkvT, nullptr, nullptr, Qc, Kc, Vt, C3, DIM);
  attn_kernel<<<dim3(SEQ / 64, NB * HEADS), 256, 0, stream>>>(Qc, Kc, Vt, att);
  // proj: M=8192, N=768, K=768 -> keep 128^2 kernel (f32 out + resid)
  gemm_bt<1, 0, 1, 0><<<dim3(DIM / 128, M_TOK / 128), 256, 0, stream>>>(
      att, wprojT, b_proj, x, x_mid, M_TOK, DIM, DIM);
  ln_kernel<<<M_TOK, 256, 0, stream>>>(x_mid, ln2_g, ln2_b, h2);
  // fc1: M=8192, N=3072, K=768 -> 32x12 = 384 blocks, bias+gelu, bf16 out
  gemm256<1, 1, 1><<<dim3(HIDDEN / 256, M_TOK / 256), 512, 0, stream>>>(
      h2, wfc1T, b_fc1, act, nullptr, nullptr, nullptr, HIDDEN, DIM);
  // fc2: M=8192, N=768, K=3072 -> split-K x4 (chunks of 768), atomicAdd onto
  // x_mid already in d_out; bias added by the z==0 chunk.
  gemm256<1, 0, 3><<<dim3(DIM / 256, M_TOK / 256, 4), 512, 0, stream>>>(
      act, wfc2T, b_fc2, outp, nullptr, nullptr, nullptr, DIM, HIDDEN);
}

// Round 7
// 404.333 us; speedup vs baseline: 1.1689x; 1.1689x over previous
//
#include <hip/hip_runtime.h>
#include <hip/hip_bf16.h>

#define DIM 768
#define HEADS 12
#define HD 64
#define HIDDEN 3072
#define SEQ 1024
#define NB 8
#define M_TOK (NB * SEQ)   // 8192 tokens
#define C3 (3 * DIM)       // 2304

typedef __attribute__((ext_vector_type(8))) short short8;    // 8 x bf16 (4 VGPRs)
typedef __attribute__((ext_vector_type(4))) short shortx4;   // 4 x bf16 (8B)
typedef __attribute__((ext_vector_type(4))) float floatx4;   // MFMA accum

__device__ __forceinline__ void gload_lds16(const void* g, void* l) {
  __builtin_amdgcn_global_load_lds((const __attribute__((address_space(1))) void*)g,
                                   (__attribute__((address_space(3))) void*)l, 16, 0, 0);
}

__device__ __forceinline__ unsigned short bf16b(float f) {
  __hip_bfloat16 h = __float2bfloat16(f);
  return *(unsigned short*)&h;
}

// ---------------------------------------------------------------------------
// Weight transpose + f32->bf16 cast: w[K][N] -> wt[N][K]
// ---------------------------------------------------------------------------
__global__ __launch_bounds__(256) void transpose_cast(
    const float* __restrict__ w, __hip_bfloat16* __restrict__ wt, int K, int N) {
  __shared__ float tile[32][33];
  const int tx = threadIdx.x & 31, ty = threadIdx.x >> 5;
  const int n0 = blockIdx.x * 32, k0 = blockIdx.y * 32;
#pragma unroll
  for (int i = 0; i < 32; i += 8)
    tile[ty + i][tx] = w[(size_t)(k0 + ty + i) * N + n0 + tx];
  __syncthreads();
#pragma unroll
  for (int i = 0; i < 32; i += 8)
    wt[(size_t)(n0 + ty + i) * K + k0 + tx] = __float2bfloat16(tile[tx][ty + i]);
}

// ---------------------------------------------------------------------------
// LayerNorm (f32 in) -> bf16 out.  One block per row of 768.
// ---------------------------------------------------------------------------
__global__ __launch_bounds__(256) void ln_kernel(
    const float* __restrict__ x, const float* __restrict__ gw,
    const float* __restrict__ bw, __hip_bfloat16* __restrict__ outp) {
  const int row = blockIdx.x;
  const int t = threadIdx.x;
  const float* xr = x + (size_t)row * DIM;
  float v0 = xr[t], v1 = xr[t + 256], v2 = xr[t + 512];
  float s = v0 + v1 + v2;
  float sq = v0 * v0 + v1 * v1 + v2 * v2;
#pragma unroll
  for (int m = 1; m < 64; m <<= 1) {
    s += __shfl_xor(s, m);
    sq += __shfl_xor(sq, m);
  }
  __shared__ float ss[4], ssq[4];
  const int wave = t >> 6, lane = t & 63;
  if (lane == 0) { ss[wave] = s; ssq[wave] = sq; }
  __syncthreads();
  s = ss[0] + ss[1] + ss[2] + ss[3];
  sq = ssq[0] + ssq[1] + ssq[2] + ssq[3];
  const float mean = s * (1.f / 768.f);
  const float var = sq * (1.f / 768.f) - mean * mean;
  const float rstd = rsqrtf(var + 1e-5f);
  __hip_bfloat16* orow = outp + (size_t)row * DIM;
  orow[t]       = __float2bfloat16((v0 - mean) * rstd * gw[t]       + bw[t]);
  orow[t + 256] = __float2bfloat16((v1 - mean) * rstd * gw[t + 256] + bw[t + 256]);
  orow[t + 512] = __float2bfloat16((v2 - mean) * rstd * gw[t + 512] + bw[t + 512]);
}

// ---------------------------------------------------------------------------
// Ring GEMM: C[M][N] = A[M][K] @ BT[N][K]^T, BK=32, 4-slot LDS ring,
// counted vmcnt(8) (2 tiles always in flight), ONE barrier per K-tile:
//   { lgkmcnt(0); vmcnt(8|4|0); s_barrier; stage(t+3); ds_reads+MFMA }
// Chunk-XOR swizzle pc^=(row>>1)&3 (pre-swizzled global source, rule #21).
// OUTMODE: 0 = f32 out + bias + resid, 1 = bf16 out (+bias/gelu),
//          2 = qkv scatter to Qc/Kc[BH,S,64] + Vt[BH,64,S].
// ---------------------------------------------------------------------------
template <int BM, int BN, int WM, int WN, int OUTMODE, int BIAS, int GELU>
__global__ __launch_bounds__(WM * WN * 64, 2) void gemm_ring(
    const __hip_bfloat16* __restrict__ A, const __hip_bfloat16* __restrict__ BT,
    const float* __restrict__ bias, const float* __restrict__ resid,
    void* __restrict__ Cout,
    __hip_bfloat16* __restrict__ Qc, __hip_bfloat16* __restrict__ Kc,
    __hip_bfloat16* __restrict__ Vt,
    int N, int K) {
  constexpr int THREADS = WM * WN * 64;
  constexpr int MF = BM / WM / 16, NF = BN / WN / 16;
  constexpr int SLOT = (BM + BN) * 32;  // bf16 elements per ring slot
  __shared__ __align__(16) __hip_bfloat16 ring[4 * SLOT];

  const int tid = threadIdx.x;
  const int wave = tid >> 6, lane = tid & 63;
  const int g = lane >> 4, fr = lane & 15;
  const int wm = wave / WN, wn = wave % WN;

  // bijective XCD swizzle (all grids have nwg % 8 == 0)
  const int gx = gridDim.x;
  const int nwg = gx * gridDim.y;
  int bi = blockIdx.y * gx + blockIdx.x;
  bi = (bi & 7) * (nwg >> 3) + (bi >> 3);
  const int m0 = (bi / gx) * BM, n0 = (bi % gx) * BN;

  // stage one BMx32 A-tile + BNx32 B-tile into ring slot (4 loads/thread)
  auto stage = [&](int slot, int kt) {
    __hip_bfloat16* dst = ring + slot * SLOT;
#pragma unroll
    for (int i = 0; i < BM * 4 / THREADS; ++i) {
      const int idx = i * THREADS + tid;
      const int row = idx >> 2, pc = idx & 3;
      const int lc = pc ^ ((row >> 1) & 3);  // pre-swizzled source
      gload_lds16(A + (size_t)(m0 + row) * K + kt + lc * 8, dst + idx * 8);
    }
    __hip_bfloat16* dstB = dst + BM * 32;
#pragma unroll
    for (int i = 0; i < BN * 4 / THREADS; ++i) {
      const int idx = i * THREADS + tid;
      const int row = idx >> 2, pc = idx & 3;
      const int lc = pc ^ ((row >> 1) & 3);
      gload_lds16(BT + (size_t)(n0 + row) * K + kt + lc * 8, dstB + idx * 8);
    }
  };

  floatx4 acc[MF][NF];
  const floatx4 zero = {0.f, 0.f, 0.f, 0.f};
#pragma unroll
  for (int mf = 0; mf < MF; ++mf)
#pragma unroll
    for (int nf = 0; nf < NF; ++nf) acc[mf][nf] = zero;

  const int NT = K >> 5;  // BK=32 tiles
  stage(0, 0);
  stage(1, 32);
  stage(2, 64);

#pragma unroll 1
  for (int t = 0; t < NT; ++t) {
    // drain my LDS reads of the previous tile before signalling
    asm volatile("s_waitcnt lgkmcnt(0)" ::: "memory");
    // counted wait: tile t landed; tiles t+1,t+2 stay in flight
    if (t < NT - 2)       asm volatile("s_waitcnt vmcnt(8)" ::: "memory");
    else if (t == NT - 2) asm volatile("s_waitcnt vmcnt(4)" ::: "memory");
    else                  asm volatile("s_waitcnt vmcnt(0)" ::: "memory");
    __builtin_amdgcn_s_barrier();
    // prefetch tile t+3 into the slot freed by tile t-1 (sealed 1 barrier ago)
    if (t + 3 < NT) stage((t + 3) & 3, (t + 3) * 32);

    const __hip_bfloat16* Ab = ring + (t & 3) * SLOT;
    const __hip_bfloat16* Bb = Ab + BM * 32;
    short8 bfr[NF];
#pragma unroll
    for (int nf = 0; nf < NF; ++nf) {
      const int row = wn * (BN / WN) + nf * 16 + fr;
      const int pc = g ^ ((row >> 1) & 3);
      bfr[nf] = *(const short8*)(Bb + row * 32 + pc * 8);
    }
    short8 afr[MF];
#pragma unroll
    for (int mf = 0; mf < MF; ++mf) {
      const int row = wm * (BM / WM) + mf * 16 + fr;
      const int pc = g ^ ((row >> 1) & 3);
      afr[mf] = *(const short8*)(Ab + row * 32 + pc * 8);
    }
    __builtin_amdgcn_s_setprio(1);
#pragma unroll
    for (int mf = 0; mf < MF; ++mf)
#pragma unroll
      for (int nf = 0; nf < NF; ++nf)
        acc[mf][nf] = __builtin_amdgcn_mfma_f32_16x16x32_bf16(
            afr[mf], bfr[nf], acc[mf][nf], 0, 0, 0);
    __builtin_amdgcn_s_setprio(0);
  }

  // ---- epilogue ----
#pragma unroll
  for (int mf = 0; mf < MF; ++mf) {
    const int row = m0 + wm * (BM / WM) + mf * 16 + g * 4;
#pragma unroll
    for (int nf = 0; nf < NF; ++nf) {
      const int col = n0 + wn * (BN / WN) + nf * 16 + fr;
      if (OUTMODE == 2) {
        const int part = (col >= 1536) ? 2 : (col >= 768 ? 1 : 0);
        const int cc = col - part * 768;
        const int h = cc >> 6, d = cc & 63;
        const int b = row >> 10, s = row & 1023;  // row%4==0: s..s+3 same b
        const size_t hb = (size_t)b * HEADS + h;
        if (part == 2) {
          shortx4 pk;
#pragma unroll
          for (int r = 0; r < 4; ++r) pk[r] = (short)bf16b(acc[mf][nf][r]);
          *(shortx4*)(Vt + (hb * HD + d) * SEQ + s) = pk;
        } else {
          __hip_bfloat16* dst = (part ? Kc : Qc) + (hb * SEQ + s) * HD + d;
#pragma unroll
          for (int r = 0; r < 4; ++r) dst[(size_t)r * HD] = __float2bfloat16(acc[mf][nf][r]);
        }
      } else {
        const float bv = BIAS ? bias[col] : 0.f;
#pragma unroll
        for (int r = 0; r < 4; ++r) {
          float c = acc[mf][nf][r] + bv;
          if (GELU) c = 0.5f * c * (1.f + erff(c * 0.70710678118f));
          const size_t off = (size_t)(row + r) * N + col;
          if (OUTMODE == 1) {
            ((__hip_bfloat16*)Cout)[off] = __float2bfloat16(c);
          } else {
            ((float*)Cout)[off] = c + resid[off];
          }
        }
      }
    }
  }
}

// ---------------------------------------------------------------------------
// Flash attention, swapped-operand + block-cooperative LDS staging (R5).
// ---------------------------------------------------------------------------
__global__ __launch_bounds__(256) void attn_kernel(
    const __hip_bfloat16* __restrict__ Qc, const __hip_bfloat16* __restrict__ Kc,
    const __hip_bfloat16* __restrict__ Vt, __hip_bfloat16* __restrict__ outp) {
  const int tid = threadIdx.x;
  const int wave = tid >> 6, lane = tid & 63;
  const int g = lane >> 4, fr = lane & 15;

  int bi = blockIdx.y * gridDim.x + blockIdx.x;
  bi = (bi & 7) * 192 + (bi >> 3);
  const int qt = bi & 15, bh = bi >> 4;
  const int b = bh / HEADS, h = bh % HEADS;
  const int q0 = qt * 64 + wave * 16;

  const __hip_bfloat16* qp = Qc + ((size_t)bh * SEQ + q0 + fr) * HD;
  const short8 qf0 = *(const short8*)(qp + g * 8);
  const short8 qf1 = *(const short8*)(qp + 32 + g * 8);

  const __hip_bfloat16* kbase = Kc + (size_t)bh * SEQ * HD;
  const __hip_bfloat16* vbase = Vt + (size_t)bh * HD * SEQ;

  __shared__ __align__(16) __hip_bfloat16 Kl[2][64 * 64];
  __shared__ __align__(16) __hip_bfloat16 Vl[2][64 * 64];
  __shared__ __align__(16) char P[4][2048];
  char* const pw = P[wave];
  const int swz = (fr & 7) << 4;
  const int rs3 = fr & 7;

  auto stage = [&](int buf, int kt) {
#pragma unroll
    for (int s = 0; s < 2; ++s) {
      const int idx = s * 256 + tid;
      const int row = idx >> 3, c = idx & 7;
      const int sc = c ^ (row & 7);
      gload_lds16(kbase + (size_t)(kt + row) * HD + sc * 8, &Kl[buf][idx * 8]);
      gload_lds16(vbase + (size_t)row * SEQ + kt + sc * 8, &Vl[buf][idx * 8]);
    }
  };

  float m_r = -1e30f, l_r = 0.f;
  floatx4 acc[4];
  const floatx4 zero = {0.f, 0.f, 0.f, 0.f};
#pragma unroll
  for (int n = 0; n < 4; ++n) acc[n] = zero;

  stage(0, 0);
  asm volatile("s_waitcnt vmcnt(0)" ::: "memory");
  __builtin_amdgcn_s_barrier();

  int cur = 0;
  for (int kt = 0; kt < SEQ; kt += 64) {
    if (kt + 64 < SEQ) stage(cur ^ 1, kt + 64);
    const __hip_bfloat16* kl = Kl[cur];
    const __hip_bfloat16* vl = Vl[cur];

    floatx4 sa[4];
#pragma unroll
    for (int t = 0; t < 4; ++t) {
      const int row = t * 16 + fr;
      const short8 k0 = *(const short8*)(kl + row * 64 + ((g ^ rs3) << 3));
      const short8 k1 = *(const short8*)(kl + row * 64 + (((4 + g) ^ rs3) << 3));
      sa[t] = __builtin_amdgcn_mfma_f32_16x16x32_bf16(k0, qf0, zero, 0, 0, 0);
      sa[t] = __builtin_amdgcn_mfma_f32_16x16x32_bf16(k1, qf1, sa[t], 0, 0, 0);
    }
    float mx = -1e30f;
#pragma unroll
    for (int t = 0; t < 4; ++t)
#pragma unroll
      for (int r = 0; r < 4; ++r) mx = fmaxf(mx, sa[t][r]);
    mx *= 0.125f;
    mx = fmaxf(mx, __shfl_xor(mx, 16));
    mx = fmaxf(mx, __shfl_xor(mx, 32));
    const float mn = fmaxf(m_r, mx);
    const float alpha = __expf(m_r - mn);
    float rsum = 0.f;
#pragma unroll
    for (int t = 0; t < 4; ++t)
#pragma unroll
      for (int r2 = 0; r2 < 4; r2 += 2) {
        const float p0 = __expf(sa[t][r2]     * 0.125f - mn);
        const float p1 = __expf(sa[t][r2 + 1] * 0.125f - mn);
        rsum += p0 + p1;
        const unsigned int word = ((unsigned int)bf16b(p1) << 16) | bf16b(p0);
        const int k = t * 16 + g * 4 + r2;
        *(unsigned int*)(pw + fr * 128 + ((k * 2) ^ swz)) = word;
      }
    rsum += __shfl_xor(rsum, 16);
    rsum += __shfl_xor(rsum, 32);
    l_r = l_r * alpha + rsum;
    m_r = mn;
#pragma unroll
    for (int n = 0; n < 4; ++n) acc[n] *= alpha;
    asm volatile("s_waitcnt lgkmcnt(0)" ::: "memory");
    __builtin_amdgcn_sched_barrier(0);
    const short8 pb0 = *(const short8*)(pw + fr * 128 + ((g * 16)      ^ swz));
    const short8 pb1 = *(const short8*)(pw + fr * 128 + ((64 + g * 16) ^ swz));
#pragma unroll
    for (int n = 0; n < 4; ++n) {
      const int d = n * 16 + fr;
      const short8 va0 = *(const short8*)(vl + d * 64 + ((g ^ rs3) << 3));
      const short8 va1 = *(const short8*)(vl + d * 64 + (((4 + g) ^ rs3) << 3));
      acc[n] = __builtin_amdgcn_mfma_f32_16x16x32_bf16(va0, pb0, acc[n], 0, 0, 0);
      acc[n] = __builtin_amdgcn_mfma_f32_16x16x32_bf16(va1, pb1, acc[n], 0, 0, 0);
    }
    asm volatile("s_waitcnt vmcnt(0) lgkmcnt(0)" ::: "memory");
    __builtin_amdgcn_s_barrier();
    cur ^= 1;
  }

  const float inv_l = 1.f / l_r;
  __hip_bfloat16* op = outp + (size_t)(b * SEQ + q0 + fr) * DIM + h * HD + g * 4;
#pragma unroll
  for (int n = 0; n < 4; ++n) {
    shortx4 pk;
#pragma unroll
    for (int r = 0; r < 4; ++r) pk[r] = (short)bf16b(acc[n][r] * inv_l);
    *(shortx4*)(op + n * 16) = pk;
  }
}

// ---------------------------------------------------------------------------
extern "C" void kernel_launch(void* const* d_in, const int* in_sizes, int n_in,
                              void* d_out, int out_size, void* d_ws, size_t ws_size,
                              hipStream_t stream) {
  (void)in_sizes; (void)n_in; (void)out_size; (void)ws_size;
  const float* x      = (const float*)d_in[0];
  const float* ln1_g  = (const float*)d_in[1];
  const float* ln1_b  = (const float*)d_in[2];
  const float* w_qkv  = (const float*)d_in[3];
  const float* w_proj = (const float*)d_in[4];
  const float* b_proj = (const float*)d_in[5];
  const float* ln2_g  = (const float*)d_in[6];
  const float* ln2_b  = (const float*)d_in[7];
  const float* w_fc1  = (const float*)d_in[8];
  const float* b_fc1  = (const float*)d_in[9];
  const float* w_fc2  = (const float*)d_in[10];
  const float* b_fc2  = (const float*)d_in[11];
  float* outp = (float*)d_out;

  char* ws = (char*)d_ws;
  size_t off = 0;
  auto alloc = [&](size_t bytes) -> void* {
    void* p = ws + off;
    off += (bytes + 255) & ~(size_t)255;
    return p;
  };
  __hip_bfloat16* h1     = (__hip_bfloat16*)alloc((size_t)M_TOK * DIM * 2);
  __hip_bfloat16* Qc     = (__hip_bfloat16*)alloc((size_t)M_TOK * DIM * 2);
  __hip_bfloat16* Kc     = (__hip_bfloat16*)alloc((size_t)M_TOK * DIM * 2);
  __hip_bfloat16* Vt     = (__hip_bfloat16*)alloc((size_t)M_TOK * DIM * 2);
  __hip_bfloat16* att    = (__hip_bfloat16*)alloc((size_t)M_TOK * DIM * 2);
  __hip_bfloat16* h2     = (__hip_bfloat16*)alloc((size_t)M_TOK * DIM * 2);
  __hip_bfloat16* act    = (__hip_bfloat16*)alloc((size_t)M_TOK * HIDDEN * 2);
  __hip_bfloat16* wqkvT  = (__hip_bfloat16*)alloc((size_t)C3 * DIM * 2);
  __hip_bfloat16* wprojT = (__hip_bfloat16*)alloc((size_t)DIM * DIM * 2);
  __hip_bfloat16* wfc1T  = (__hip_bfloat16*)alloc((size_t)HIDDEN * DIM * 2);
  __hip_bfloat16* wfc2T  = (__hip_bfloat16*)alloc((size_t)DIM * HIDDEN * 2);
  float* x_mid = outp;  // mid-residual lives in d_out (fully rewritten each call)

  transpose_cast<<<dim3(C3 / 32, DIM / 32), 256, 0, stream>>>(w_qkv, wqkvT, DIM, C3);
  transpose_cast<<<dim3(DIM / 32, DIM / 32), 256, 0, stream>>>(w_proj, wprojT, DIM, DIM);
  transpose_cast<<<dim3(HIDDEN / 32, DIM / 32), 256, 0, stream>>>(w_fc1, wfc1T, DIM, HIDDEN);
  transpose_cast<<<dim3(DIM / 32, HIDDEN / 32), 256, 0, stream>>>(w_fc2, wfc2T, HIDDEN, DIM);

  ln_kernel<<<M_TOK, 256, 0, stream>>>(x, ln1_g, ln1_b, h1);
  // qkv: 256^2 ring, scatter epilogue. grid 9x32 = 288
  gemm_ring<256, 256, 2, 4, 2, 0, 0><<<dim3(C3 / 256, M_TOK / 256), 512, 0, stream>>>(
      h1, wqkvT, nullptr, nullptr, nullptr, Qc, Kc, Vt, C3, DIM);
  attn_kernel<<<dim3(SEQ / 64, NB * HEADS), 256, 0, stream>>>(Qc, Kc, Vt, att);
  // proj: 128^2 ring (2 blocks/CU), f32 + bias + resid(x). grid 6x64 = 384
  gemm_ring<128, 128, 2, 2, 0, 1, 0><<<dim3(DIM / 128, M_TOK / 128), 256, 0, stream>>>(
      att, wprojT, b_proj, x, x_mid, nullptr, nullptr, nullptr, DIM, DIM);
  ln_kernel<<<M_TOK, 256, 0, stream>>>(x_mid, ln2_g, ln2_b, h2);
  // fc1: 256^2 ring, bias + gelu, bf16 out. grid 12x32 = 384
  gemm_ring<256, 256, 2, 4, 1, 1, 1><<<dim3(HIDDEN / 256, M_TOK / 256), 512, 0, stream>>>(
      h2, wfc1T, b_fc1, nullptr, act, nullptr, nullptr, nullptr, HIDDEN, DIM);
  // fc2: 128^2 ring, K=3072, f32 + bias + resid(x_mid). grid 6x64 = 384
  gemm_ring<128, 128, 2, 2, 0, 1, 0><<<dim3(DIM / 128, M_TOK / 128), 256, 0, stream>>>(
      act, wfc2T, b_fc2, x_mid, outp, nullptr, nullptr, nullptr, DIM, HIDDEN);
}

// Round 8
// 379.547 us; speedup vs baseline: 1.2452x; 1.0653x over previous
//
#include <hip/hip_runtime.h>
#include <hip/hip_bf16.h>

#define DIM 768
#define HEADS 12
#define HD 64
#define HIDDEN 3072
#define SEQ 1024
#define NB 8
#define M_TOK (NB * SEQ)   // 8192 tokens
#define C3 (3 * DIM)       // 2304

typedef __attribute__((ext_vector_type(8))) short short8;    // 8 x bf16 (4 VGPRs)
typedef __attribute__((ext_vector_type(4))) short shortx4;   // 4 x bf16 (8B)
typedef __attribute__((ext_vector_type(4))) float floatx4;   // MFMA accum

__device__ __forceinline__ void gload_lds16(const void* g, void* l) {
  __builtin_amdgcn_global_load_lds((const __attribute__((address_space(1))) void*)g,
                                   (__attribute__((address_space(3))) void*)l, 16, 0, 0);
}

__device__ __forceinline__ unsigned short bf16b(float f) {
  __hip_bfloat16 h = __float2bfloat16(f);
  return *(unsigned short*)&h;
}

// ---------------------------------------------------------------------------
// Weight transpose + f32->bf16 cast: w[K][N] -> wt[N][K]
// ---------------------------------------------------------------------------
__global__ __launch_bounds__(256) void transpose_cast(
    const float* __restrict__ w, __hip_bfloat16* __restrict__ wt, int K, int N) {
  __shared__ float tile[32][33];
  const int tx = threadIdx.x & 31, ty = threadIdx.x >> 5;
  const int n0 = blockIdx.x * 32, k0 = blockIdx.y * 32;
#pragma unroll
  for (int i = 0; i < 32; i += 8)
    tile[ty + i][tx] = w[(size_t)(k0 + ty + i) * N + n0 + tx];
  __syncthreads();
#pragma unroll
  for (int i = 0; i < 32; i += 8)
    wt[(size_t)(n0 + ty + i) * K + k0 + tx] = __float2bfloat16(tile[tx][ty + i]);
}

// ---------------------------------------------------------------------------
// LayerNorm (f32 in) -> bf16 out.  One block per row of 768.
// ---------------------------------------------------------------------------
__global__ __launch_bounds__(256) void ln_kernel(
    const float* __restrict__ x, const float* __restrict__ gw,
    const float* __restrict__ bw, __hip_bfloat16* __restrict__ outp) {
  const int row = blockIdx.x;
  const int t = threadIdx.x;
  const float* xr = x + (size_t)row * DIM;
  float v0 = xr[t], v1 = xr[t + 256], v2 = xr[t + 512];
  float s = v0 + v1 + v2;
  float sq = v0 * v0 + v1 * v1 + v2 * v2;
#pragma unroll
  for (int m = 1; m < 64; m <<= 1) {
    s += __shfl_xor(s, m);
    sq += __shfl_xor(sq, m);
  }
  __shared__ float ss[4], ssq[4];
  const int wave = t >> 6, lane = t & 63;
  if (lane == 0) { ss[wave] = s; ssq[wave] = sq; }
  __syncthreads();
  s = ss[0] + ss[1] + ss[2] + ss[3];
  sq = ssq[0] + ssq[1] + ssq[2] + ssq[3];
  const float mean = s * (1.f / 768.f);
  const float var = sq * (1.f / 768.f) - mean * mean;
  const float rstd = rsqrtf(var + 1e-5f);
  __hip_bfloat16* orow = outp + (size_t)row * DIM;
  orow[t]       = __float2bfloat16((v0 - mean) * rstd * gw[t]       + bw[t]);
  orow[t + 256] = __float2bfloat16((v1 - mean) * rstd * gw[t + 256] + bw[t + 256]);
  orow[t + 512] = __float2bfloat16((v2 - mean) * rstd * gw[t + 512] + bw[t + 512]);
}

// ---------------------------------------------------------------------------
// Ring GEMM: C[M][N] = A[M][K] @ BT[N][K]^T, BK=32, 3-slot LDS ring,
// counted vmcnt(L) (tile t+1 always in flight), ONE barrier per K-tile:
//   { lgkmcnt(0); vmcnt(L|0); s_barrier; stage(t+2); ds_reads+MFMA }
// 4-wave blocks: 128x256 ring = 72KB -> 2 blocks/CU; 128x128 = 48KB -> 3/CU.
// Chunk-XOR swizzle pc^=(row>>1)&3 (pre-swizzled global source, rule #21).
// OUTMODE: 0 = f32 out + bias + resid, 1 = bf16 out (+bias/gelu),
//          2 = qkv scatter to Qc/Kc[BH,S,64] + Vt[BH,64,S].
// ---------------------------------------------------------------------------
template <int BM, int BN, int WM, int WN, int OUTMODE, int BIAS, int GELU>
__global__ __launch_bounds__(WM * WN * 64, 2) void gemm_ring(
    const __hip_bfloat16* __restrict__ A, const __hip_bfloat16* __restrict__ BT,
    const float* __restrict__ bias, const float* __restrict__ resid,
    void* __restrict__ Cout,
    __hip_bfloat16* __restrict__ Qc, __hip_bfloat16* __restrict__ Kc,
    __hip_bfloat16* __restrict__ Vt,
    int N, int K) {
  constexpr int THREADS = WM * WN * 64;
  constexpr int MF = BM / WM / 16, NF = BN / WN / 16;
  constexpr int SLOT = (BM + BN) * 32;               // bf16 elems per ring slot
  constexpr int L = (BM + BN) * 4 / THREADS;         // loads/thread per stage
  __shared__ __align__(16) __hip_bfloat16 ring[3 * SLOT];

  const int tid = threadIdx.x;
  const int wave = tid >> 6, lane = tid & 63;
  const int g = lane >> 4, fr = lane & 15;
  const int wm = wave / WN, wn = wave % WN;

  // bijective XCD swizzle (all grids have nwg % 8 == 0)
  const int gx = gridDim.x;
  const int nwg = gx * gridDim.y;
  int bi = blockIdx.y * gx + blockIdx.x;
  bi = (bi & 7) * (nwg >> 3) + (bi >> 3);
  const int m0 = (bi / gx) * BM, n0 = (bi % gx) * BN;

  // stage one BMx32 A-tile + BNx32 B-tile into ring slot
  auto stage = [&](int slot, int kt) {
    __hip_bfloat16* dst = ring + slot * SLOT;
#pragma unroll
    for (int i = 0; i < BM * 4 / THREADS; ++i) {
      const int idx = i * THREADS + tid;
      const int row = idx >> 2, pc = idx & 3;
      const int lc = pc ^ ((row >> 1) & 3);  // pre-swizzled source
      gload_lds16(A + (size_t)(m0 + row) * K + kt + lc * 8, dst + idx * 8);
    }
    __hip_bfloat16* dstB = dst + BM * 32;
#pragma unroll
    for (int i = 0; i < BN * 4 / THREADS; ++i) {
      const int idx = i * THREADS + tid;
      const int row = idx >> 2, pc = idx & 3;
      const int lc = pc ^ ((row >> 1) & 3);
      gload_lds16(BT + (size_t)(n0 + row) * K + kt + lc * 8, dstB + idx * 8);
    }
  };

  floatx4 acc[MF][NF];
  const floatx4 zero = {0.f, 0.f, 0.f, 0.f};
#pragma unroll
  for (int mf = 0; mf < MF; ++mf)
#pragma unroll
    for (int nf = 0; nf < NF; ++nf) acc[mf][nf] = zero;

  const int NT = K >> 5;  // BK=32 tiles
  stage(0, 0);
  stage(1, 32);
  int slot = 0, nslot = 2;

#pragma unroll 1
  for (int t = 0; t < NT; ++t) {
    // drain my LDS reads of the previous tile before signalling
    asm volatile("s_waitcnt lgkmcnt(0)" ::: "memory");
    // counted wait: tile t landed; tile t+1 stays in flight
    if (t < NT - 1) {
      if constexpr (L == 6) asm volatile("s_waitcnt vmcnt(6)" ::: "memory");
      else                  asm volatile("s_waitcnt vmcnt(4)" ::: "memory");
    } else {
      asm volatile("s_waitcnt vmcnt(0)" ::: "memory");
    }
    __builtin_amdgcn_s_barrier();
    // prefetch tile t+2 into the slot freed by tile t-1 (sealed by this barrier)
    if (t + 2 < NT) stage(nslot, (t + 2) * 32);

    const __hip_bfloat16* Ab = ring + slot * SLOT;
    const __hip_bfloat16* Bb = Ab + BM * 32;
    slot = (slot + 1 == 3) ? 0 : slot + 1;
    nslot = (nslot + 1 == 3) ? 0 : nslot + 1;

    short8 bfr[NF];
#pragma unroll
    for (int nf = 0; nf < NF; ++nf) {
      const int row = wn * (BN / WN) + nf * 16 + fr;
      const int pc = g ^ ((row >> 1) & 3);
      bfr[nf] = *(const short8*)(Bb + row * 32 + pc * 8);
    }
    short8 afr[MF];
#pragma unroll
    for (int mf = 0; mf < MF; ++mf) {
      const int row = wm * (BM / WM) + mf * 16 + fr;
      const int pc = g ^ ((row >> 1) & 3);
      afr[mf] = *(const short8*)(Ab + row * 32 + pc * 8);
    }
    __builtin_amdgcn_s_setprio(1);
#pragma unroll
    for (int mf = 0; mf < MF; ++mf)
#pragma unroll
      for (int nf = 0; nf < NF; ++nf)
        acc[mf][nf] = __builtin_amdgcn_mfma_f32_16x16x32_bf16(
            afr[mf], bfr[nf], acc[mf][nf], 0, 0, 0);
    __builtin_amdgcn_s_setprio(0);
  }

  // ---- epilogue ----
#pragma unroll
  for (int mf = 0; mf < MF; ++mf) {
    const int row = m0 + wm * (BM / WM) + mf * 16 + g * 4;
#pragma unroll
    for (int nf = 0; nf < NF; ++nf) {
      const int col = n0 + wn * (BN / WN) + nf * 16 + fr;
      if (OUTMODE == 2) {
        const int part = (col >= 1536) ? 2 : (col >= 768 ? 1 : 0);
        const int cc = col - part * 768;
        const int h = cc >> 6, d = cc & 63;
        const int b = row >> 10, s = row & 1023;  // row%4==0: s..s+3 same b
        const size_t hb = (size_t)b * HEADS + h;
        if (part == 2) {
          shortx4 pk;
#pragma unroll
          for (int r = 0; r < 4; ++r) pk[r] = (short)bf16b(acc[mf][nf][r]);
          *(shortx4*)(Vt + (hb * HD + d) * SEQ + s) = pk;
        } else {
          __hip_bfloat16* dst = (part ? Kc : Qc) + (hb * SEQ + s) * HD + d;
#pragma unroll
          for (int r = 0; r < 4; ++r) dst[(size_t)r * HD] = __float2bfloat16(acc[mf][nf][r]);
        }
      } else {
        const float bv = BIAS ? bias[col] : 0.f;
#pragma unroll
        for (int r = 0; r < 4; ++r) {
          float c = acc[mf][nf][r] + bv;
          if (GELU) c = 0.5f * c * (1.f + erff(c * 0.70710678118f));
          const size_t off = (size_t)(row + r) * N + col;
          if (OUTMODE == 1) {
            ((__hip_bfloat16*)Cout)[off] = __float2bfloat16(c);
          } else {
            ((float*)Cout)[off] = c + resid[off];
          }
        }
      }
    }
  }
}

// ---------------------------------------------------------------------------
// Flash attention, swapped-operand + block-cooperative LDS staging (R5).
// ---------------------------------------------------------------------------
__global__ __launch_bounds__(256) void attn_kernel(
    const __hip_bfloat16* __restrict__ Qc, const __hip_bfloat16* __restrict__ Kc,
    const __hip_bfloat16* __restrict__ Vt, __hip_bfloat16* __restrict__ outp) {
  const int tid = threadIdx.x;
  const int wave = tid >> 6, lane = tid & 63;
  const int g = lane >> 4, fr = lane & 15;

  int bi = blockIdx.y * gridDim.x + blockIdx.x;
  bi = (bi & 7) * 192 + (bi >> 3);
  const int qt = bi & 15, bh = bi >> 4;
  const int b = bh / HEADS, h = bh % HEADS;
  const int q0 = qt * 64 + wave * 16;

  const __hip_bfloat16* qp = Qc + ((size_t)bh * SEQ + q0 + fr) * HD;
  const short8 qf0 = *(const short8*)(qp + g * 8);
  const short8 qf1 = *(const short8*)(qp + 32 + g * 8);

  const __hip_bfloat16* kbase = Kc + (size_t)bh * SEQ * HD;
  const __hip_bfloat16* vbase = Vt + (size_t)bh * HD * SEQ;

  __shared__ __align__(16) __hip_bfloat16 Kl[2][64 * 64];
  __shared__ __align__(16) __hip_bfloat16 Vl[2][64 * 64];
  __shared__ __align__(16) char P[4][2048];
  char* const pw = P[wave];
  const int swz = (fr & 7) << 4;
  const int rs3 = fr & 7;

  auto stage = [&](int buf, int kt) {
#pragma unroll
    for (int s = 0; s < 2; ++s) {
      const int idx = s * 256 + tid;
      const int row = idx >> 3, c = idx & 7;
      const int sc = c ^ (row & 7);
      gload_lds16(kbase + (size_t)(kt + row) * HD + sc * 8, &Kl[buf][idx * 8]);
      gload_lds16(vbase + (size_t)row * SEQ + kt + sc * 8, &Vl[buf][idx * 8]);
    }
  };

  float m_r = -1e30f, l_r = 0.f;
  floatx4 acc[4];
  const floatx4 zero = {0.f, 0.f, 0.f, 0.f};
#pragma unroll
  for (int n = 0; n < 4; ++n) acc[n] = zero;

  stage(0, 0);
  asm volatile("s_waitcnt vmcnt(0)" ::: "memory");
  __builtin_amdgcn_s_barrier();

  int cur = 0;
  for (int kt = 0; kt < SEQ; kt += 64) {
    if (kt + 64 < SEQ) stage(cur ^ 1, kt + 64);
    const __hip_bfloat16* kl = Kl[cur];
    const __hip_bfloat16* vl = Vl[cur];

    floatx4 sa[4];
#pragma unroll
    for (int t = 0; t < 4; ++t) {
      const int row = t * 16 + fr;
      const short8 k0 = *(const short8*)(kl + row * 64 + ((g ^ rs3) << 3));
      const short8 k1 = *(const short8*)(kl + row * 64 + (((4 + g) ^ rs3) << 3));
      sa[t] = __builtin_amdgcn_mfma_f32_16x16x32_bf16(k0, qf0, zero, 0, 0, 0);
      sa[t] = __builtin_amdgcn_mfma_f32_16x16x32_bf16(k1, qf1, sa[t], 0, 0, 0);
    }
    float mx = -1e30f;
#pragma unroll
    for (int t = 0; t < 4; ++t)
#pragma unroll
      for (int r = 0; r < 4; ++r) mx = fmaxf(mx, sa[t][r]);
    mx *= 0.125f;
    mx = fmaxf(mx, __shfl_xor(mx, 16));
    mx = fmaxf(mx, __shfl_xor(mx, 32));
    const float mn = fmaxf(m_r, mx);
    const float alpha = __expf(m_r - mn);
    float rsum = 0.f;
#pragma unroll
    for (int t = 0; t < 4; ++t)
#pragma unroll
      for (int r2 = 0; r2 < 4; r2 += 2) {
        const float p0 = __expf(sa[t][r2]     * 0.125f - mn);
        const float p1 = __expf(sa[t][r2 + 1] * 0.125f - mn);
        rsum += p0 + p1;
        const unsigned int word = ((unsigned int)bf16b(p1) << 16) | bf16b(p0);
        const int k = t * 16 + g * 4 + r2;
        *(unsigned int*)(pw + fr * 128 + ((k * 2) ^ swz)) = word;
      }
    rsum += __shfl_xor(rsum, 16);
    rsum += __shfl_xor(rsum, 32);
    l_r = l_r * alpha + rsum;
    m_r = mn;
#pragma unroll
    for (int n = 0; n < 4; ++n) acc[n] *= alpha;
    asm volatile("s_waitcnt lgkmcnt(0)" ::: "memory");
    __builtin_amdgcn_sched_barrier(0);
    const short8 pb0 = *(const short8*)(pw + fr * 128 + ((g * 16)      ^ swz));
    const short8 pb1 = *(const short8*)(pw + fr * 128 + ((64 + g * 16) ^ swz));
#pragma unroll
    for (int n = 0; n < 4; ++n) {
      const int d = n * 16 + fr;
      const short8 va0 = *(const short8*)(vl + d * 64 + ((g ^ rs3) << 3));
      const short8 va1 = *(const short8*)(vl + d * 64 + (((4 + g) ^ rs3) << 3));
      acc[n] = __builtin_amdgcn_mfma_f32_16x16x32_bf16(va0, pb0, acc[n], 0, 0, 0);
      acc[n] = __builtin_amdgcn_mfma_f32_16x16x32_bf16(va1, pb1, acc[n], 0, 0, 0);
    }
    asm volatile("s_waitcnt vmcnt(0) lgkmcnt(0)" ::: "memory");
    __builtin_amdgcn_s_barrier();
    cur ^= 1;
  }

  const float inv_l = 1.f / l_r;
  __hip_bfloat16* op = outp + (size_t)(b * SEQ + q0 + fr) * DIM + h * HD + g * 4;
#pragma unroll
  for (int n = 0; n < 4; ++n) {
    shortx4 pk;
#pragma unroll
    for (int r = 0; r < 4; ++r) pk[r] = (short)bf16b(acc[n][r] * inv_l);
    *(shortx4*)(op + n * 16) = pk;
  }
}

// ---------------------------------------------------------------------------
extern "C" void kernel_launch(void* const* d_in, const int* in_sizes, int n_in,
                              void* d_out, int out_size, void* d_ws, size_t ws_size,
                              hipStream_t stream) {
  (void)in_sizes; (void)n_in; (void)out_size; (void)ws_size;
  const float* x      = (const float*)d_in[0];
  const float* ln1_g  = (const float*)d_in[1];
  const float* ln1_b  = (const float*)d_in[2];
  const float* w_qkv  = (const float*)d_in[3];
  const float* w_proj = (const float*)d_in[4];
  const float* b_proj = (const float*)d_in[5];
  const float* ln2_g  = (const float*)d_in[6];
  const float* ln2_b  = (const float*)d_in[7];
  const float* w_fc1  = (const float*)d_in[8];
  const float* b_fc1  = (const float*)d_in[9];
  const float* w_fc2  = (const float*)d_in[10];
  const float* b_fc2  = (const float*)d_in[11];
  float* outp = (float*)d_out;

  char* ws = (char*)d_ws;
  size_t off = 0;
  auto alloc = [&](size_t bytes) -> void* {
    void* p = ws + off;
    off += (bytes + 255) & ~(size_t)255;
    return p;
  };
  __hip_bfloat16* h1     = (__hip_bfloat16*)alloc((size_t)M_TOK * DIM * 2);
  __hip_bfloat16* Qc     = (__hip_bfloat16*)alloc((size_t)M_TOK * DIM * 2);
  __hip_bfloat16* Kc     = (__hip_bfloat16*)alloc((size_t)M_TOK * DIM * 2);
  __hip_bfloat16* Vt     = (__hip_bfloat16*)alloc((size_t)M_TOK * DIM * 2);
  __hip_bfloat16* att    = (__hip_bfloat16*)alloc((size_t)M_TOK * DIM * 2);
  __hip_bfloat16* h2     = (__hip_bfloat16*)alloc((size_t)M_TOK * DIM * 2);
  __hip_bfloat16* act    = (__hip_bfloat16*)alloc((size_t)M_TOK * HIDDEN * 2);
  __hip_bfloat16* wqkvT  = (__hip_bfloat16*)alloc((size_t)C3 * DIM * 2);
  __hip_bfloat16* wprojT = (__hip_bfloat16*)alloc((size_t)DIM * DIM * 2);
  __hip_bfloat16* wfc1T  = (__hip_bfloat16*)alloc((size_t)HIDDEN * DIM * 2);
  __hip_bfloat16* wfc2T  = (__hip_bfloat16*)alloc((size_t)DIM * HIDDEN * 2);
  float* x_mid = outp;  // mid-residual lives in d_out (fully rewritten each call)

  transpose_cast<<<dim3(C3 / 32, DIM / 32), 256, 0, stream>>>(w_qkv, wqkvT, DIM, C3);
  transpose_cast<<<dim3(DIM / 32, DIM / 32), 256, 0, stream>>>(w_proj, wprojT, DIM, DIM);
  transpose_cast<<<dim3(HIDDEN / 32, DIM / 32), 256, 0, stream>>>(w_fc1, wfc1T, DIM, HIDDEN);
  transpose_cast<<<dim3(DIM / 32, HIDDEN / 32), 256, 0, stream>>>(w_fc2, wfc2T, HIDDEN, DIM);

  ln_kernel<<<M_TOK, 256, 0, stream>>>(x, ln1_g, ln1_b, h1);
  // qkv: 128x256 ring3 (2 blocks/CU), scatter epilogue. grid 9x64 = 576
  gemm_ring<128, 256, 1, 4, 2, 0, 0><<<dim3(C3 / 256, M_TOK / 128), 256, 0, stream>>>(
      h1, wqkvT, nullptr, nullptr, nullptr, Qc, Kc, Vt, C3, DIM);
  attn_kernel<<<dim3(SEQ / 64, NB * HEADS), 256, 0, stream>>>(Qc, Kc, Vt, att);
  // proj: 128x128 ring3 (3 blocks/CU), f32 + bias + resid(x). grid 6x64 = 384
  gemm_ring<128, 128, 2, 2, 0, 1, 0><<<dim3(DIM / 128, M_TOK / 128), 256, 0, stream>>>(
      att, wprojT, b_proj, x, x_mid, nullptr, nullptr, nullptr, DIM, DIM);
  ln_kernel<<<M_TOK, 256, 0, stream>>>(x_mid, ln2_g, ln2_b, h2);
  // fc1: 128x256 ring3 (2 blocks/CU), bias + gelu, bf16 out. grid 12x64 = 768
  gemm_ring<128, 256, 1, 4, 1, 1, 1><<<dim3(HIDDEN / 256, M_TOK / 128), 256, 0, stream>>>(
      h2, wfc1T, b_fc1, nullptr, act, nullptr, nullptr, nullptr, HIDDEN, DIM);
  // fc2: 128x128 ring3 (3 blocks/CU), K=3072, f32 + bias + resid(x_mid). grid 6x64 = 384
  gemm_ring<128, 128, 2, 2, 0, 1, 0><<<dim3(DIM / 128, M_TOK / 128), 256, 0, stream>>>(
      act, wfc2T, b_fc2, x_mid, outp, nullptr, nullptr, nullptr, DIM, HIDDEN);
}